// Round 3
// baseline (75743.054 us; speedup 1.0000x reference)
//
#include <hip/hip_runtime.h>

#define B 128
#define L 256
#define E 256
#define H 512
#define NBLK 256
#define NTHR 512

// ---- ws float offsets ----
#define WS_CTX   0u             // [B][L][H]            16777216
#define WS_GA    16777216u      // [8][2048][128]        2097152
#define WS_GD    18874368u      // [16][512][128]        1048576
#define WS_HCAR  19922944u      // [H][B]  h carry         65536
#define WS_HT    19988480u      // [H][B]  lstm h_t        65536
#define WS_CST   20054016u      // [H][B]  c state         65536
#define WS_XT    20119552u      // [E][B]  current x       32768
#define WS_INP   20152320u      // [B][H]  attn query      65536
#define WS_HID   20217856u      // [H][B]  attn context    65536
#define WS_MASK  20283392u      // [B][L]                  32768
#define WS_BAR   20316160u      // barrier cnt/gen

// ---- d_out float offsets ----
#define OUT_ALPHA 0u
#define OUT_PTR   8388608u
#define OUT_H     8421376u
#define OUT_C     8486912u

#define L2E 1.4426950408889634f

__device__ __forceinline__ float fast_rcp(float x) { return __builtin_amdgcn_rcpf(x); }

// tanh(x) = 1 - 2/(e^{2x}+1)  (exact both signs; inf-safe)
__device__ __forceinline__ float ftanh(float x) {
  float e = exp2f(x * (2.0f * L2E));
  return 1.0f - 2.0f * fast_rcp(e + 1.0f);
}
// sigmoid(x) = 1/(1+e^{-x})  (inf-safe)
__device__ __forceinline__ float fsig(float x) {
  float e = exp2f(-x * L2E);
  return fast_rcp(1.0f + e);
}

// ---- device-wide sense barrier (agent scope, cross-XCD safe) ----
__device__ __forceinline__ void grid_sync(unsigned* bar, unsigned* gen) {
  __syncthreads();
  if (threadIdx.x == 0) {
    unsigned g = __hip_atomic_load(gen, __ATOMIC_RELAXED, __HIP_MEMORY_SCOPE_AGENT);
    __threadfence();  // release: wb L2 so other XCDs see this block's writes
    unsigned a = __hip_atomic_fetch_add(bar, 1u, __ATOMIC_ACQ_REL, __HIP_MEMORY_SCOPE_AGENT);
    if (a == NBLK - 1u) {
      __hip_atomic_store(bar, 0u, __ATOMIC_RELAXED, __HIP_MEMORY_SCOPE_AGENT);
      __hip_atomic_store(gen, g + 1u, __ATOMIC_RELEASE, __HIP_MEMORY_SCOPE_AGENT);
    } else {
      while (__hip_atomic_load(gen, __ATOMIC_RELAXED, __HIP_MEMORY_SCOPE_AGENT) == g)
        __builtin_amdgcn_s_sleep(1);
    }
    __threadfence();  // acquire: invalidate stale L1/L2 before reading others' data
  }
  __syncthreads();
}

// ================= precompute ctx[b][l][g] (unchanged, proven) =================
__global__ __launch_bounds__(256) void k_ctx(const float* __restrict__ context,
                                             const float* __restrict__ Wc,
                                             const float* __restrict__ bc,
                                             float* __restrict__ ws) {
  __shared__ float a_lds[64][33];
  __shared__ float b_lds[32][68];
  int t = threadIdx.x;
  int m0 = blockIdx.x * 64;
  int n0 = blockIdx.y * 64;
  int tx = t & 15, ty = t >> 4;
  float acc[4][4] = {};
  for (int kc = 0; kc < 16; ++kc) {
    int k0 = kc * 32;
    __syncthreads();
#pragma unroll
    for (int i = 0; i < 2; ++i) {
      int f4 = t + i * 256;
      int mm = f4 >> 3;
      int k4 = (f4 & 7) * 4;
      float4 v = *(const float4*)&context[(size_t)(m0 + mm) * H + k0 + k4];
      a_lds[mm][k4] = v.x; a_lds[mm][k4 + 1] = v.y; a_lds[mm][k4 + 2] = v.z; a_lds[mm][k4 + 3] = v.w;
    }
#pragma unroll
    for (int i = 0; i < 2; ++i) {
      int f4 = t + i * 256;
      int nn = f4 >> 3;
      int k4 = (f4 & 7) * 4;
      float4 v = *(const float4*)&Wc[(size_t)(n0 + nn) * H + k0 + k4];
      b_lds[k4][nn] = v.x; b_lds[k4 + 1][nn] = v.y; b_lds[k4 + 2][nn] = v.z; b_lds[k4 + 3][nn] = v.w;
    }
    __syncthreads();
#pragma unroll
    for (int kk = 0; kk < 32; ++kk) {
      float4 bv = *(const float4*)&b_lds[kk][tx * 4];
      float a0 = a_lds[ty * 4 + 0][kk], a1 = a_lds[ty * 4 + 1][kk];
      float a2 = a_lds[ty * 4 + 2][kk], a3 = a_lds[ty * 4 + 3][kk];
      acc[0][0] += a0 * bv.x; acc[0][1] += a0 * bv.y; acc[0][2] += a0 * bv.z; acc[0][3] += a0 * bv.w;
      acc[1][0] += a1 * bv.x; acc[1][1] += a1 * bv.y; acc[1][2] += a1 * bv.z; acc[1][3] += a1 * bv.w;
      acc[2][0] += a2 * bv.x; acc[2][1] += a2 * bv.y; acc[2][2] += a2 * bv.z; acc[2][3] += a2 * bv.w;
      acc[3][0] += a3 * bv.x; acc[3][1] += a3 * bv.y; acc[3][2] += a3 * bv.z; acc[3][3] += a3 * bv.w;
    }
  }
  float b0v = bc[n0 + tx * 4], b1v = bc[n0 + tx * 4 + 1], b2v = bc[n0 + tx * 4 + 2], b3v = bc[n0 + tx * 4 + 3];
#pragma unroll
  for (int i = 0; i < 4; ++i) {
    size_t o = WS_CTX + (size_t)(m0 + ty * 4 + i) * H + n0 + tx * 4;
    float4 v; v.x = acc[i][0] + b0v; v.y = acc[i][1] + b1v; v.z = acc[i][2] + b2v; v.w = acc[i][3] + b3v;
    *(float4*)&ws[o] = v;
  }
}

// ================= init state (transposed) + barrier reset =================
__global__ __launch_bounds__(256) void k_init(const float* __restrict__ dec_h,
                                              const float* __restrict__ dec_c,
                                              const float* __restrict__ dec_in,
                                              float* __restrict__ ws) {
  int flat = blockIdx.x * 256 + threadIdx.x;
  if (flat == 0) {
    unsigned* bar = (unsigned*)(ws + WS_BAR);
    bar[0] = 0u; bar[1] = 0u;
  }
  if (flat < 65536) {
    int h = flat >> 7, b = flat & 127;
    ws[WS_HCAR + flat] = dec_h[(size_t)b * H + h];
  } else if (flat < 131072) {
    int f2 = flat - 65536;
    int h = f2 >> 7, b = f2 & 127;
    ws[WS_CST + f2] = dec_c[(size_t)b * H + h];
  } else if (flat < 163840) {
    int f2 = flat - 131072;
    int k = f2 >> 7, b = f2 & 127;
    ws[WS_XT + f2] = dec_in[(size_t)b * E + k];
  } else if (flat < 196608) {
    ws[WS_MASK + (flat - 163840)] = 1.0f;
  }
}

// ================= persistent fused decoder =================
__global__ __launch_bounds__(512, 2) void k_main(
    const float* __restrict__ Wi2h, const float* __restrict__ bi2h,
    const float* __restrict__ Wh2h, const float* __restrict__ bh2h,
    const float* __restrict__ Wout, const float* __restrict__ bout,
    const float* __restrict__ Winp, const float* __restrict__ binp,
    const float* __restrict__ Vv,   const float* __restrict__ emb,
    float* __restrict__ ws,         float* __restrict__ out) {
  __shared__ float smem[6656];
  __shared__ float s_m, s_den;
  __shared__ int s_mi, s_cnt;
  __shared__ int s_wc[4], s_wb[4];

  unsigned* bar = (unsigned*)(ws + WS_BAR);
  unsigned* gen = bar + 1;

  const int bid = blockIdx.x;
  const int t = threadIdx.x;
  const int wv = t >> 6;        // wave 0..7
  const int ln = t & 63;        // lane

  for (int step = 0; step < L; ++step) {
    // ======== A1: gates partials  GA[ks][j][b] (j = gate*512+u), K-split 8 ========
    {
      const int tile = bid & 31, ksA = bid >> 5;   // 32 u-tiles x 8 K-slices
      const int u0 = tile * 16;
      const int q = ln >> 5;                        // row-quad select
      const int b4 = (ln & 31) * 4;
      float4 a0 = {0,0,0,0}, a1 = a0, a2 = a0, a3 = a0;
#pragma unroll
      for (int ch = 0; ch < 3; ++ch) {
        const int kg0 = ksA * 96 + ch * 32;
        __syncthreads();
#pragma unroll
        for (int i = 0; i < 2; ++i) {              // stage act 32x128
          int id = t + i * 512;
          int kk = id >> 5, bb = (id & 31) * 4;
          int kg = kg0 + kk;
          float4 v;
          if (kg < 256) v = *(const float4*)&ws[WS_XT + (size_t)kg * 128 + bb];
          else          v = *(const float4*)&ws[WS_HCAR + (size_t)(kg - 256) * 128 + bb];
          *(float4*)&smem[kk * 128 + bb] = v;
        }
#pragma unroll
        for (int i = 0; i < 4; ++i) {              // stage w 64rows x 32k
          int fl = t + i * 512;
          int kk = fl & 31, rr = fl >> 5;
          int j = (rr >> 4) * 512 + u0 + (rr & 15);
          int kg = kg0 + kk;
          float wval = (kg < 256) ? Wi2h[(size_t)j * 256 + kg]
                                  : Wh2h[(size_t)j * 512 + (kg - 256)];
          smem[4096 + ((rr >> 3) * 2 + ((rr >> 2) & 1)) * 128 + kk * 4 + (rr & 3)] = wval;
        }
        __syncthreads();
        const float* sw = &smem[4096 + (wv * 2 + q) * 128];
#pragma unroll
        for (int kk = 0; kk < 32; ++kk) {
          float4 av = *(const float4*)&smem[kk * 128 + b4];
          float4 w4 = *(const float4*)&sw[kk * 4];
          a0.x += w4.x * av.x; a0.y += w4.x * av.y; a0.z += w4.x * av.z; a0.w += w4.x * av.w;
          a1.x += w4.y * av.x; a1.y += w4.y * av.y; a1.z += w4.y * av.z; a1.w += w4.y * av.w;
          a2.x += w4.z * av.x; a2.y += w4.z * av.y; a2.z += w4.z * av.z; a2.w += w4.z * av.w;
          a3.x += w4.w * av.x; a3.y += w4.w * av.y; a3.z += w4.w * av.z; a3.w += w4.w * av.w;
        }
      }
      const int rrb = wv * 8 + q * 4;
      {
        int j0 = ((rrb + 0) >> 4) * 512 + u0 + ((rrb + 0) & 15);
        int j1 = ((rrb + 1) >> 4) * 512 + u0 + ((rrb + 1) & 15);
        int j2 = ((rrb + 2) >> 4) * 512 + u0 + ((rrb + 2) & 15);
        int j3 = ((rrb + 3) >> 4) * 512 + u0 + ((rrb + 3) & 15);
        *(float4*)&ws[WS_GA + ((size_t)ksA * 2048 + j0) * 128 + b4] = a0;
        *(float4*)&ws[WS_GA + ((size_t)ksA * 2048 + j1) * 128 + b4] = a1;
        *(float4*)&ws[WS_GA + ((size_t)ksA * 2048 + j2) * 128 + b4] = a2;
        *(float4*)&ws[WS_GA + ((size_t)ksA * 2048 + j3) * 128 + b4] = a3;
      }
    }
    grid_sync(bar, gen);

    // ======== A2: reduce partials + LSTM elementwise ========
    if (t < 256) {
      int fl = bid * 256 + t;
      int u = fl >> 7, b = fl & 127;
      float s4[4];
#pragma unroll
      for (int g = 0; g < 4; ++g) {
        int j = g * 512 + u;
        float a = bi2h[j] + bh2h[j];
#pragma unroll
        for (int p = 0; p < 8; ++p) a += ws[WS_GA + ((size_t)p * 2048 + j) * 128 + b];
        s4[g] = a;
      }
      size_t cb = WS_CST + (size_t)u * 128 + b;
      float c_old = ws[cb];
      float c_new = fsig(s4[1]) * c_old + fsig(s4[0]) * ftanh(s4[2]);
      ws[cb] = c_new;
      ws[WS_HT + (size_t)u * 128 + b] = fsig(s4[3]) * ftanh(c_new);
    }
    grid_sync(bar, gen);

    // ======== B: inp[b][g] = W_inp @ h_t + b_inp  (2 g-rows per block) ========
    {
      const int r2 = t >> 8, kh = (t >> 7) & 1, bb = t & 127;
      const int g = bid * 2 + r2;
      const float* wrow = &Winp[(size_t)g * 512 + kh * 256];
      const float* arow = &ws[WS_HT + (size_t)kh * 256 * 128 + bb];
      float acc = 0.f;
#pragma unroll 16
      for (int kk = 0; kk < 256; ++kk) acc += wrow[kk] * arow[(size_t)kk * 128];
      smem[t] = acc;
      __syncthreads();
      if (t < 256) {
        int rr2 = t >> 7, b2 = t & 127;
        float v = smem[rr2 * 256 + b2] + smem[rr2 * 256 + 128 + b2] + binp[bid * 2 + rr2];
        ws[WS_INP + (size_t)b2 * 512 + bid * 2 + rr2] = v;
      }
    }
    grid_sync(bar, gen);

    // ======== C: attention (one block per b, bid<128) ========
    if (bid < 128) {
      const int b = bid;
      float* s_inp   = smem;              // 512
      float* s_v     = smem + 512;        // 512
      float* s_mask  = smem + 1024;       // 256
      float* s_alpha = smem + 1280;       // 256
      float* s_sc    = smem + 1536;       // 512 ([l*2+gh])
      float* s_red   = smem + 2048;       // 4
      int*   s_redi  = (int*)(smem + 2052); // 4
      int*   s_listI = (int*)(smem + 2056); // 256

      s_inp[t] = ws[WS_INP + (size_t)b * 512 + t];
      s_v[t] = Vv[t];
      if (t < 256) s_mask[t] = ws[WS_MASK + (size_t)b * 256 + t];
      __syncthreads();
      // packed valid-l list (deterministic, l-ascending)
      bool validl = (t < 256) && (s_mask[t] != 0.f);
      unsigned long long bal = __ballot(validl);
      if (t < 256 && (t & 63) == 0) s_wc[t >> 6] = (int)__popcll(bal);
      __syncthreads();
      if (t == 0) {
        int base = 0;
#pragma unroll
        for (int i2 = 0; i2 < 4; ++i2) { s_wb[i2] = base; base += s_wc[i2]; }
        s_cnt = base;
      }
      __syncthreads();
      if (validl) {
        int idx = s_wb[t >> 6] + (int)__popcll(bal & ((1ull << (t & 63)) - 1ull));
        s_listI[idx] = t;
      }
      __syncthreads();
      const int cnt = s_cnt;

      // scores over packed slots
      {
        int slot = t & 255, gh = t >> 8;
        if (slot < cnt) {
          int l = s_listI[slot];
          const float* cbase = &ws[WS_CTX + ((size_t)b * 256 + l) * 512 + gh * 256];
          float part = 0.f;
#pragma unroll 4
          for (int i = 0; i < 64; ++i) {
            float4 c4 = *(const float4*)&cbase[i * 4];
            float4 v4 = *(const float4*)&s_v[gh * 256 + i * 4];
            float4 p4 = *(const float4*)&s_inp[gh * 256 + i * 4];
            part += v4.x * ftanh(p4.x + c4.x);
            part += v4.y * ftanh(p4.y + c4.y);
            part += v4.z * ftanh(p4.z + c4.z);
            part += v4.w * ftanh(p4.w + c4.w);
          }
          s_sc[l * 2 + gh] = part;
        }
      }
      __syncthreads();
      float sc = 0.f; bool valid = false;
      if (t < 256) {
        sc = s_sc[t * 2] + s_sc[t * 2 + 1];
        valid = (s_mask[t] != 0.f);
        float bs = valid ? sc : -INFINITY;
        int bi = t;
#pragma unroll
        for (int off = 32; off > 0; off >>= 1) {
          float os = __shfl_down(bs, off);
          int oi = __shfl_down(bi, off);
          if (os > bs || (os == bs && oi < bi)) { bs = os; bi = oi; }
        }
        if ((t & 63) == 0) { s_red[t >> 6] = bs; s_redi[t >> 6] = bi; }
      }
      __syncthreads();
      if (t == 0) {
        float m = s_red[0]; int mi = s_redi[0];
#pragma unroll
        for (int w = 1; w < 4; ++w) {
          if (s_red[w] > m || (s_red[w] == m && s_redi[w] < mi)) { m = s_red[w]; mi = s_redi[w]; }
        }
        s_m = m; s_mi = mi;
      }
      __syncthreads();
      float e = 0.f;
      if (t < 256) {
        e = valid ? exp2f((sc - s_m) * L2E) : 0.f;
        float ssum = e;
#pragma unroll
        for (int off = 32; off > 0; off >>= 1) ssum += __shfl_down(ssum, off);
        if ((t & 63) == 0) s_red[t >> 6] = ssum;
      }
      __syncthreads();
      if (t == 0) s_den = s_red[0] + s_red[1] + s_red[2] + s_red[3];
      __syncthreads();
      const int mi = s_mi;
      if (t < 256) {
        float alpha = e / s_den;
        s_alpha[t] = alpha;
        out[OUT_ALPHA + ((size_t)b * 256 + step) * 256 + t] = alpha;
        ws[WS_XT + (size_t)t * 128 + b] = emb[((size_t)b * 256 + mi) * 256 + t];
      }
      if (t == 0) {
        out[OUT_PTR + (size_t)b * 256 + step] = (float)mi;
        ws[WS_MASK + (size_t)b * 256 + mi] = 0.f;
      }
      __syncthreads();
      // hidden[h] = sum_l alpha_l * ctx[b][l][h]
      {
        float h0 = 0.f, h1 = 0.f, h2 = 0.f, h3 = 0.f;
        int i = 0;
        for (; i + 4 <= cnt; i += 4) {
          int l0 = s_listI[i], l1 = s_listI[i + 1], l2 = s_listI[i + 2], l3 = s_listI[i + 3];
          h0 += s_alpha[l0] * ws[WS_CTX + ((size_t)b * 256 + l0) * 512 + t];
          h1 += s_alpha[l1] * ws[WS_CTX + ((size_t)b * 256 + l1) * 512 + t];
          h2 += s_alpha[l2] * ws[WS_CTX + ((size_t)b * 256 + l2) * 512 + t];
          h3 += s_alpha[l3] * ws[WS_CTX + ((size_t)b * 256 + l3) * 512 + t];
        }
        for (; i < cnt; ++i) {
          int l0 = s_listI[i];
          h0 += s_alpha[l0] * ws[WS_CTX + ((size_t)b * 256 + l0) * 512 + t];
        }
        ws[WS_HID + (size_t)t * 128 + b] = ((h0 + h1) + (h2 + h3));
      }
    }
    grid_sync(bar, gen);

    // ======== D1: hnew partials  GD[ks][r][b], K-split 16 over [hidden;h_t] ========
    {
      const int rt = bid & 15, ksD = bid >> 4;   // 16 r-tiles x 16 K-slices
      const int r0 = rt * 32;
      const int b2 = ln * 2;
      const float* asrc = (ksD < 8) ? &ws[WS_HID + (size_t)ksD * 64 * 128]
                                    : &ws[WS_HT + (size_t)(ksD - 8) * 64 * 128];
      float2 c0 = {0,0}, c1 = {0,0}, c2 = {0,0}, c3 = {0,0};
#pragma unroll
      for (int ch = 0; ch < 2; ++ch) {
        __syncthreads();
#pragma unroll
        for (int i = 0; i < 2; ++i) {            // stage act 32x128
          int id = t + i * 512;
          int kk = id >> 5, bb = (id & 31) * 4;
          *(float4*)&smem[kk * 128 + bb] = *(const float4*)&asrc[(size_t)(ch * 32 + kk) * 128 + bb];
        }
#pragma unroll
        for (int i = 0; i < 2; ++i) {            // stage w 32rows x 32k
          int fl = t + i * 512;
          int kk = fl & 31, r = fl >> 5;
          smem[4096 + ((r >> 2) * 32 + kk) * 4 + (r & 3)] =
              Wout[(size_t)(r0 + r) * 1024 + ksD * 64 + ch * 32 + kk];
        }
        __syncthreads();
        const float* sw = &smem[4096 + wv * 128];
#pragma unroll
        for (int kk = 0; kk < 32; ++kk) {
          float2 a2v = *(const float2*)&smem[kk * 128 + b2];
          float4 w4 = *(const float4*)&sw[kk * 4];
          c0.x += w4.x * a2v.x; c0.y += w4.x * a2v.y;
          c1.x += w4.y * a2v.x; c1.y += w4.y * a2v.y;
          c2.x += w4.z * a2v.x; c2.y += w4.z * a2v.y;
          c3.x += w4.w * a2v.x; c3.y += w4.w * a2v.y;
        }
      }
      *(float2*)&ws[WS_GD + ((size_t)ksD * 512 + r0 + wv * 4 + 0) * 128 + b2] = c0;
      *(float2*)&ws[WS_GD + ((size_t)ksD * 512 + r0 + wv * 4 + 1) * 128 + b2] = c1;
      *(float2*)&ws[WS_GD + ((size_t)ksD * 512 + r0 + wv * 4 + 2) * 128 + b2] = c2;
      *(float2*)&ws[WS_GD + ((size_t)ksD * 512 + r0 + wv * 4 + 3) * 128 + b2] = c3;
    }
    grid_sync(bar, gen);

    // ======== D2: reduce + tanh -> HCAR ========
    if (t < 256) {
      int fl = bid * 256 + t;
      int r = fl >> 7, b = fl & 127;
      float s = bout[r];
#pragma unroll
      for (int p = 0; p < 16; ++p) s += ws[WS_GD + ((size_t)p * 512 + r) * 128 + b];
      ws[WS_HCAR + (size_t)r * 128 + b] = ftanh(s);
    }
    grid_sync(bar, gen);
  }

  // ======== final h/c outputs ========
  if (t < 256) {
    int fl = bid * 256 + t;
    int r = fl >> 7, b = fl & 127;
    out[OUT_H + (size_t)b * 512 + r] = ws[WS_HCAR + (size_t)r * 128 + b];
    out[OUT_C + (size_t)b * 512 + r] = ws[WS_CST + (size_t)r * 128 + b];
  }
}

extern "C" void kernel_launch(void* const* d_in, const int* in_sizes, int n_in,
                              void* d_out, int out_size, void* d_ws, size_t ws_size,
                              hipStream_t stream) {
  (void)in_sizes; (void)n_in; (void)out_size; (void)ws_size;
  const float* emb    = (const float*)d_in[0];
  const float* dec_in = (const float*)d_in[1];
  const float* dec_h  = (const float*)d_in[2];
  const float* dec_c  = (const float*)d_in[3];
  const float* ctx_in = (const float*)d_in[4];
  const float* W_i2h  = (const float*)d_in[5];
  const float* b_i2h  = (const float*)d_in[6];
  const float* W_h2h  = (const float*)d_in[7];
  const float* b_h2h  = (const float*)d_in[8];
  const float* W_out  = (const float*)d_in[9];
  const float* b_out  = (const float*)d_in[10];
  const float* W_inp  = (const float*)d_in[11];
  const float* b_inp  = (const float*)d_in[12];
  const float* W_ctx  = (const float*)d_in[13];
  const float* b_ctx  = (const float*)d_in[14];
  const float* Vv     = (const float*)d_in[15];
  float* out = (float*)d_out;
  float* ws  = (float*)d_ws;

  k_ctx<<<dim3(512, 8), 256, 0, stream>>>(ctx_in, W_ctx, b_ctx, ws);
  k_init<<<768, 256, 0, stream>>>(dec_h, dec_c, dec_in, ws);
  k_main<<<NBLK, NTHR, 0, stream>>>(W_i2h, b_i2h, W_h2h, b_h2h, W_out, b_out,
                                    W_inp, b_inp, Vv, emb, ws, out);
}